// Round 9
// baseline (123.727 us; speedup 1.0000x reference)
//
#include <hip/hip_runtime.h>
#include <math.h>

// Problem constants (fixed by setup_inputs)
#define Nn 32
#define Cc 128
#define Ss 4096
#define Kk 64
#define NCHUNK 16
#define SCHUNK (Ss / NCHUNK)   // 256 pixels per block
#define ST 64                  // pixels per subtile
#define NSUB (SCHUNK / ST)     // 4 subtiles per block
#define BLK 256

// LDS strides
#define XCS 72    // xC [c][s] stride in ushorts (s-contig, 16B-aligned rows)
#define XTS 136   // xT [s][c] stride in ushorts (c-contig, 16B-aligned rows)
#define LKS 68    // scr [s][k] stride in floats (aliases xT region: 68 dw == 136 u16)
#define AS  72    // aB [k][s] stride in ushorts
#define RS  20    // red stride in floats (16B-aligned rows for b128 reads)

typedef __attribute__((ext_vector_type(8))) short short8;   // bf16x8 MFMA frag
typedef __attribute__((ext_vector_type(4))) float float4v;  // fp32x4 MFMA acc

__device__ __forceinline__ unsigned f2bf(float f) {
    unsigned u = __builtin_bit_cast(unsigned, f);
    return (u + 0x7fffu + ((u >> 16) & 1u)) >> 16;   // RNE f32->bf16
}

// Fused main (unchanged from round 8 — passed, best-known ~39.5us).
// Per subtile (3 barriers): P0 stage reg-direct dual-layout; P1 per-lane invn ->
// GEMM1 (wave=pixel-tile, wfragT[4][4] regs) -> in-register softmax -> aB;
// P2 GEMM2 persistent acc. Commit via plain stores to per-chunk vladp/asump.
// MFMA 16x16x32 bf16 layouts (HW-verified): A[m=lane&15][k=quad*8+j],
// B[k=quad*8+j][n=lane&15], D col=lane&15 row=4*quad+reg.
__global__ __launch_bounds__(BLK, 2) void netvlad_main(
    const float* __restrict__ x,
    const float* __restrict__ conv_w,
    const float* __restrict__ conv_b,
    float* __restrict__ vladp,   // [NCHUNK][Nn][Kk][Cc]  16 MB
    float* __restrict__ asump,   // [NCHUNK][Nn][Kk]      128 KB
    float* __restrict__ out)     // zeroed by block (0,0) for finalize atomics
{
    __shared__ __align__(16) unsigned short xC[Cc * XCS];  // 18432 B
    __shared__ __align__(16) unsigned short xT[ST * XTS];  // 17408 B (scr alias)
    __shared__ __align__(16) unsigned short aB[Kk * AS];   //  9216 B
    __shared__ __align__(16) float red[ST * RS];           //  5120 B

    const int t     = threadIdx.x;
    const int n     = blockIdx.y;
    const int chunk = blockIdx.x;
    const int w    = t >> 6;      // wave id = pixel-tile (GEMM1) / k-tile (GEMM2)
    const int l    = t & 63;
    const int m    = l & 15;
    const int quad = l >> 4;

    // ---- out is poisoned each call: block (0,0) zeroes it ----
    if (chunk == 0 && n == 0) {
        float4 z4 = make_float4(0.f, 0.f, 0.f, 0.f);
#pragma unroll
        for (int i = 0; i < 4; ++i)
            ((float4*)out)[t + 256 * i] = z4;
    }

    // ---- one-time: conv_w A-frags for ALL 4 k-tiles + bias (regs) ----
    short8 wfragT[4][4];   // [kt][ks]
    float  bias_s[16];     // [4*kt + r] = conv_b[16kt + 4quad + r]
#pragma unroll
    for (int kt = 0; kt < 4; ++kt) {
        const float* wr_ = conv_w + (16 * kt + m) * Cc;
#pragma unroll
        for (int ks = 0; ks < 4; ++ks) {
            float4 wa = *(const float4*)(wr_ + 32 * ks + 8 * quad);
            float4 wb = *(const float4*)(wr_ + 32 * ks + 8 * quad + 4);
            union { short8 s8; unsigned u[4]; } W_;
            W_.u[0] = f2bf(wa.x) | (f2bf(wa.y) << 16);
            W_.u[1] = f2bf(wa.z) | (f2bf(wa.w) << 16);
            W_.u[2] = f2bf(wb.x) | (f2bf(wb.y) << 16);
            W_.u[3] = f2bf(wb.z) | (f2bf(wb.w) << 16);
            wfragT[kt][ks] = W_.s8;
        }
        float4 bq = *(const float4*)(conv_b + 16 * kt + 4 * quad);
        bias_s[4 * kt + 0] = bq.x;
        bias_s[4 * kt + 1] = bq.y;
        bias_s[4 * kt + 2] = bq.z;
        bias_s[4 * kt + 3] = bq.w;
    }

    float4v acc[8];               // VLAD acc: 16k x 128c per wave, persistent
#pragma unroll
    for (int nt = 0; nt < 8; ++nt) acc[nt] = (float4v){0.f, 0.f, 0.f, 0.f};
    float asum_part[16];          // [4*kt + r] partial a-sums for pixel s_l
#pragma unroll
    for (int j = 0; j < 16; ++j) asum_part[j] = 0.f;

    const float* xn = x + (size_t)n * Cc * Ss;

    // ---- stage tile: 8 consecutive channels (8*crow..+7) x 4 pixels ----
    const int sq   = (t & 15) << 2;
    const int crow = t >> 4;
    const float* xbase = xn + (size_t)(8 * crow) * Ss + chunk * SCHUNK + sq;
    float4 pf[8];
#pragma unroll
    for (int r = 0; r < 8; ++r)
        pf[r] = *(const float4*)(xbase + (size_t)r * Ss);

    const int s_l = 16 * w + m;   // this lane's pixel (GEMM1/softmax)

    for (int sub = 0; sub < NSUB; ++sub) {
        __syncthreads();  // prior GEMM2 reads of xC/aB done

        // ---- P0: stage regs -> xC [c][s], xT [s][c], red ssq partials ----
        {
            unsigned bf[8][4];
            float sp0 = 0.f, sp1 = 0.f, sp2 = 0.f, sp3 = 0.f;
#pragma unroll
            for (int r = 0; r < 8; ++r) {
                float4 v = pf[r];
                sp0 += v.x * v.x; sp1 += v.y * v.y;
                sp2 += v.z * v.z; sp3 += v.w * v.w;
                bf[r][0] = f2bf(v.x); bf[r][1] = f2bf(v.y);
                bf[r][2] = f2bf(v.z); bf[r][3] = f2bf(v.w);
            }
#pragma unroll
            for (int r = 0; r < 8; ++r) {
                uint2 pk = make_uint2(bf[r][0] | (bf[r][1] << 16),
                                      bf[r][2] | (bf[r][3] << 16));
                *(uint2*)&xC[(8 * crow + r) * XCS + sq] = pk;
            }
#pragma unroll
            for (int i = 0; i < 4; ++i) {
                uint4 dd;
                dd.x = bf[0][i] | (bf[1][i] << 16);
                dd.y = bf[2][i] | (bf[3][i] << 16);
                dd.z = bf[4][i] | (bf[5][i] << 16);
                dd.w = bf[6][i] | (bf[7][i] << 16);
                *(uint4*)&xT[(sq + i) * XTS + 8 * crow] = dd;
            }
            red[(sq + 0) * RS + crow] = sp0;
            red[(sq + 1) * RS + crow] = sp1;
            red[(sq + 2) * RS + crow] = sp2;
            red[(sq + 3) * RS + crow] = sp3;
        }
        if (sub < NSUB - 1) {
#pragma unroll
            for (int r = 0; r < 8; ++r)
                pf[r] = *(const float4*)(xbase + (size_t)r * Ss + (sub + 1) * ST);
        }
        __syncthreads();

        // ---- P1: per-lane invn -> GEMM1 -> in-register softmax -> aB ----
        {
            const float* rp = &red[s_l * RS];
            float4 q0 = *(const float4*)(rp + 0);
            float4 q1 = *(const float4*)(rp + 4);
            float4 q2 = *(const float4*)(rp + 8);
            float4 q3 = *(const float4*)(rp + 12);
            float tot = ((q0.x + q0.y) + (q0.z + q0.w))
                      + ((q1.x + q1.y) + (q1.z + q1.w))
                      + ((q2.x + q2.y) + (q2.z + q2.w))
                      + ((q3.x + q3.y) + (q3.z + q3.w));
            float invl = 1.0f / fmaxf(sqrtf(tot), 1e-12f);

            short8 Bfr[4];
#pragma unroll
            for (int ks = 0; ks < 4; ++ks)
                Bfr[ks] = *(const short8*)&xT[s_l * XTS + 32 * ks + 8 * quad];
            float4v Lr[4];
#pragma unroll
            for (int kt = 0; kt < 4; ++kt) Lr[kt] = (float4v){0.f, 0.f, 0.f, 0.f};
#pragma unroll
            for (int kt = 0; kt < 4; ++kt) {
#pragma unroll
                for (int ks = 0; ks < 4; ++ks)
                    Lr[kt] = __builtin_amdgcn_mfma_f32_16x16x32_bf16(
                        wfragT[kt][ks], Bfr[ks], Lr[kt], 0, 0, 0);
            }

            float lv[16];
#pragma unroll
            for (int kt = 0; kt < 4; ++kt) {
                lv[4 * kt + 0] = Lr[kt][0] * invl + bias_s[4 * kt + 0];
                lv[4 * kt + 1] = Lr[kt][1] * invl + bias_s[4 * kt + 1];
                lv[4 * kt + 2] = Lr[kt][2] * invl + bias_s[4 * kt + 2];
                lv[4 * kt + 3] = Lr[kt][3] * invl + bias_s[4 * kt + 3];
            }
            float mx = lv[0];
#pragma unroll
            for (int j = 1; j < 16; ++j) mx = fmaxf(mx, lv[j]);
            mx = fmaxf(mx, __shfl_xor(mx, 16));   // team lanes {m,m+16,m+32,m+48}
            mx = fmaxf(mx, __shfl_xor(mx, 32));
            float e[16];
            float lsum = 0.f;
#pragma unroll
            for (int j = 0; j < 16; ++j) { e[j] = __expf(lv[j] - mx); lsum += e[j]; }
            lsum += __shfl_xor(lsum, 16);
            lsum += __shfl_xor(lsum, 32);
            float itot = 1.0f / lsum;
            float sca  = itot * invl;   // fold invn into a' (x in GEMM2 is raw)
#pragma unroll
            for (int kt = 0; kt < 4; ++kt) {
#pragma unroll
                for (int r = 0; r < 4; ++r) {
                    float ev = e[4 * kt + r];
                    asum_part[4 * kt + r] += ev * itot;
                    aB[(16 * kt + 4 * quad + r) * AS + s_l] =
                        (unsigned short)f2bf(ev * sca);
                }
            }
        }
        __syncthreads();

        // ---- P2: GEMM2: V[16w+k][c] += a'[k][s] x rawX^T[s][c] ----
#pragma unroll
        for (int ks = 0; ks < 2; ++ks) {
            short8 af = *(const short8*)&aB[(16 * w + m) * AS + 32 * ks + 8 * quad];
#pragma unroll
            for (int nt = 0; nt < 8; ++nt) {
                short8 bf_ = *(const short8*)&xC[(16 * nt + m) * XCS + 32 * ks + 8 * quad];
                acc[nt] = __builtin_amdgcn_mfma_f32_16x16x32_bf16(af, bf_, acc[nt], 0, 0, 0);
            }
        }
    }

    // ---- commit vlad partials as PLAIN STORES: lane holds D[k=16w+4quad+r][c=16nt+m]
    {
        float* vb = vladp + ((((size_t)chunk * Nn + n) * Kk) + 16 * w + 4 * quad) * Cc + m;
#pragma unroll
        for (int nt = 0; nt < 8; ++nt) {
            vb[0 * Cc + 16 * nt] = acc[nt].x;
            vb[1 * Cc + 16 * nt] = acc[nt].y;
            vb[2 * Cc + 16 * nt] = acc[nt].z;
            vb[3 * Cc + 16 * nt] = acc[nt].w;
        }
    }

    // ---- block-reduce asum then plain store per k (xT region as f32 scratch) ----
    __syncthreads();
    {
        float* scr = (float*)xT;
#pragma unroll
        for (int kt = 0; kt < 4; ++kt) {
#pragma unroll
            for (int r = 0; r < 4; ++r)
                scr[s_l * LKS + 16 * kt + 4 * quad + r] = asum_part[4 * kt + r];
        }
    }
    __syncthreads();
    if (t < Kk) {
        float* scr = (float*)xT;
        float s_ = 0.f;
        for (int p2 = 0; p2 < ST; ++p2) s_ += scr[p2 * LKS + t];
        asump[((size_t)chunk * Nn + n) * Kk + t] = s_;
    }
}

// Finalize v2 — 4x MLP. Grid 1024 blocks = (n2, kq of 2 k's).
// Phase 1: 256 threads = 2 kl x 4 chunk-teams x 32 c4; each thread sums 4
//   chunks (coalesced 512B/wave segments) -> LDS. asum staged concurrently.
// Phase 2 (wave 0): combine teams, d = v - a*c, ssq via intra-32-lane
//   shfl_xor reduce (masks <=16 stay in half), scale, 4 atomicAdds into
//   main-zeroed out.
__global__ __launch_bounds__(BLK) void netvlad_final(
    const float* __restrict__ vladp,
    const float* __restrict__ asump,
    const float* __restrict__ centroids,
    const float* __restrict__ fc_w,
    float* __restrict__ out)
{
    __shared__ __align__(16) float4 part[2 * 4 * 32];  // [kl][ct][c4] 4 KB
    __shared__ float ared[2][16];

    const int t   = threadIdx.x;
    const int bid = blockIdx.x;
    const int n2  = bid >> 5;
    const int kq  = bid & 31;
    const int kl  = t >> 7;          // 0..1
    const int tt  = t & 127;
    const int ct  = tt >> 5;         // 0..3 chunk-team
    const int c4  = tt & 31;         // float4 column
    const int k2  = 2 * kq + kl;

    // phase 1: sum 4 chunks for (k2, c4)
    {
        float4 v = make_float4(0.f, 0.f, 0.f, 0.f);
        const float* vp = vladp + ((size_t)n2 * Kk + k2) * Cc + 4 * c4;
#pragma unroll
        for (int i = 0; i < 4; ++i) {
            float4 u = *(const float4*)(vp + (size_t)(4 * ct + i) * Nn * Kk * Cc);
            v.x += u.x; v.y += u.y; v.z += u.z; v.w += u.w;
        }
        part[(kl * 4 + ct) * 32 + c4] = v;
    }
    // concurrent asum chunk staging (16 lanes per kl)
    if (tt < 16)
        ared[kl][tt] = asump[((size_t)tt * Nn + n2) * Kk + k2];
    __syncthreads();

    // phase 2: wave 0 only (lanes 0..31 = kl 0, 32..63 = kl 1)
    if (t < 64) {
        const int kl2 = t >> 5;
        const int c4b = t & 31;
        const int k2b = 2 * kq + kl2;

        float4 v = part[(kl2 * 4 + 0) * 32 + c4b];
#pragma unroll
        for (int ct2 = 1; ct2 < 4; ++ct2) {
            float4 u = part[(kl2 * 4 + ct2) * 32 + c4b];
            v.x += u.x; v.y += u.y; v.z += u.z; v.w += u.w;
        }
        float a2 = 0.f;
#pragma unroll
        for (int i = 0; i < 16; ++i) a2 += ared[kl2][i];

        float4 cv = *(const float4*)(centroids + (size_t)k2b * Cc + 4 * c4b);
        float dx = v.x - a2 * cv.x;
        float dy = v.y - a2 * cv.y;
        float dz = v.z - a2 * cv.z;
        float dw = v.w - a2 * cv.w;

        float ssq = dx * dx + dy * dy + dz * dz + dw * dw;
        ssq += __shfl_xor(ssq, 1);
        ssq += __shfl_xor(ssq, 2);
        ssq += __shfl_xor(ssq, 4);
        ssq += __shfl_xor(ssq, 8);
        ssq += __shfl_xor(ssq, 16);   // masks<32 keep the 32-lane halves separate

        float sc = fc_w[k2b] / fmaxf(sqrtf(ssq), 1e-12f);
        float* ob = out + n2 * Cc + 4 * c4b;
        atomicAdd(ob + 0, sc * dx);
        atomicAdd(ob + 1, sc * dy);
        atomicAdd(ob + 2, sc * dz);
        atomicAdd(ob + 3, sc * dw);
    }
}

extern "C" void kernel_launch(void* const* d_in, const int* in_sizes, int n_in,
                              void* d_out, int out_size, void* d_ws, size_t ws_size,
                              hipStream_t stream) {
    (void)in_sizes; (void)n_in; (void)out_size; (void)ws_size;
    const float* x         = (const float*)d_in[0];
    const float* conv_w    = (const float*)d_in[1];
    const float* conv_b    = (const float*)d_in[2];
    const float* centroids = (const float*)d_in[3];
    const float* fc_w      = (const float*)d_in[4];
    float* out = (float*)d_out;

    float* vladp = (float*)d_ws;                                   // 16 MB
    float* asump = vladp + (size_t)NCHUNK * Nn * Kk * Cc;          // 128 KB

    dim3 grid(NCHUNK, Nn);
    netvlad_main<<<grid, BLK, 0, stream>>>(x, conv_w, conv_b, vladp, asump, out);
    netvlad_final<<<dim3(Nn * 32), BLK, 0, stream>>>(vladp, asump, centroids, fc_w, out);
}